// Round 4
// baseline (297.993 us; speedup 1.0000x reference)
//
#include <hip/hip_runtime.h>
#include <math.h>

namespace {

typedef float f32x4 __attribute__((ext_vector_type(4)));

__device__ __forceinline__ float rcp_f(float x) { return __builtin_amdgcn_rcpf(x); }

// z/(exp(z)-1), with 1 - z/2 for |z| < 1e-4 (matches reference efun)
__device__ __forceinline__ float efun(float z) {
    float e = __expf(z);
    float big = z * rcp_f(e - 1.0f);
    float small = 1.0f - 0.5f * z;
    return (fabsf(z) < 1e-4f) ? small : big;
}

struct F5 { float dV, dn, dm, dh, dp; };

__device__ __forceinline__ F5 hh(float V, float n, float m, float h, float p, float I_in) {
    // VT = -60 folded into the offsets.
    float a_n = 0.16f  * efun(-0.2f  * (V + 45.0f));           // 0.032/0.2
    float a_m = 1.28f  * efun(-0.25f * (V + 47.0f));           // 0.32/0.25
    float b_n = 0.5f   * __expf((V + 50.0f) * -0.025f);        // 0.5*exp(-(V+50)/40)
    float a_h = 0.128f * __expf((V + 43.0f) * (-1.0f / 18.0f));

    // Shared exponential for beta_m and beta_h: z = 0.2(V+20), e = exp(z)
    //   beta_m = 1.4*efun(z);  beta_h = 4/(1+exp(-z)) = 4 - 4/(e+1)  (overflow-safe)
    float zb = 0.2f * (V + 20.0f);
    float eb = __expf(zb);
    float bm_big = zb * rcp_f(eb - 1.0f);
    float b_m = 1.4f * ((fabsf(zb) < 1e-4f) ? (1.0f - 0.5f * zb) : bm_big);
    float b_h = 4.0f - 4.0f * rcp_f(eb + 1.0f);

    float ekv = -107.0f - V;   // E_K - V
    float m3  = m * m * m;
    float n2  = n * n;

    F5 r;
    r.dV = 4.0f  * m3 * h * (53.0f - V)     // gbar_Na * m^3 * h * (E_Na - V)
         + 1.5f  * (n2 * n2) * ekv          // gbar_K * n^4 * (E_K - V)
         + 0.07f * p * ekv                  // gbar_M * p * (E_K - V)
         + 0.1f  * (-70.0f - V)             // g_leak * (E_leak - V)
         + I_in;                            // C_MEM = 1

    // dx = (a/(a+b) - x)*(a+b) == a - (a+b)*x  — rcp-free form
    float sn = a_n + b_n; r.dn = a_n - sn * n;
    float sm = a_m + b_m; r.dm = a_m - sm * m;
    float sh = a_h + b_h; r.dh = a_h - sh * h;

    // p gate: one exp. e5 = exp(0.05*v1); exp(-0.05*v1)=rcp(e5); exp(-0.1*v1)=rcp(e5)^2
    float v1   = V + 35.0f;
    float e5   = __expf(0.05f * v1);
    float re5  = rcp_f(e5);
    float pinf = rcp_f(1.0f + re5 * re5);
    float itau = (3.3f * e5 + re5) * (1.0f / 600.0f);
    r.dp = (pinf - p) * itau;
    return r;
}

__device__ __forceinline__ void hh4(f32x4 V, f32x4 n, f32x4 m, f32x4 h, f32x4 p,
                                    float I_in, f32x4 o[5]) {
    F5 a = hh(V.x, n.x, m.x, h.x, p.x, I_in);
    F5 b = hh(V.y, n.y, m.y, h.y, p.y, I_in);
    F5 c = hh(V.z, n.z, m.z, h.z, p.z, I_in);
    F5 d = hh(V.w, n.w, m.w, h.w, p.w, I_in);
    o[0].x = a.dV; o[0].y = b.dV; o[0].z = c.dV; o[0].w = d.dV;
    o[1].x = a.dn; o[1].y = b.dn; o[1].z = c.dn; o[1].w = d.dn;
    o[2].x = a.dm; o[2].y = b.dm; o[2].z = c.dm; o[2].w = d.dm;
    o[3].x = a.dh; o[3].y = b.dh; o[3].z = c.dh; o[3].w = d.dh;
    o[4].x = a.dp; o[4].y = b.dp; o[4].z = c.dp; o[4].w = d.dp;
}

// 8 elements per thread as two blocked halves (i and i+nb8). All 10 loads are
// issued up front: 2x the in-flight memory per wave vs the 4-elem version,
// which is the lever for the 10-stream mixed R/W pattern. Each half's accesses
// stay perfectly coalesced (lane-contiguous 16B).
__global__ __launch_bounds__(256) void hh_kernel(
    const int* __restrict__ tptr,
    const f32x4* __restrict__ V4, const f32x4* __restrict__ n4,
    const f32x4* __restrict__ m4, const f32x4* __restrict__ h4,
    const f32x4* __restrict__ p4,
    f32x4* __restrict__ out4, int nb8, int nb4, float i_in_level)
{
    int i = blockIdx.x * blockDim.x + threadIdx.x;
    if (i >= nb8) return;
    int j = i + nb8;

    // I_in = level if (t > I_ON=0 and t < I_OFF=inf) else 0
    float t = (float)(*tptr);
    float I_in = (t > 0.0f) ? i_in_level : 0.0f;

    // Issue all 10 loads before any compute.
    f32x4 V0 = V4[i], n0 = n4[i], m0 = m4[i], h0 = h4[i], p0 = p4[i];
    f32x4 V1 = V4[j], n1 = n4[j], m1 = m4[j], h1 = h4[j], p1 = p4[j];

    f32x4 o[5];
    hh4(V0, n0, m0, h0, p0, I_in, o);
    out4[i          ] = o[0];
    out4[i +     nb4] = o[1];
    out4[i + 2 * nb4] = o[2];
    out4[i + 3 * nb4] = o[3];
    out4[i + 4 * nb4] = o[4];

    hh4(V1, n1, m1, h1, p1, I_in, o);
    out4[j          ] = o[0];
    out4[j +     nb4] = o[1];
    out4[j + 2 * nb4] = o[2];
    out4[j + 3 * nb4] = o[3];
    out4[j + 4 * nb4] = o[4];
}

} // anonymous namespace

extern "C" void kernel_launch(void* const* d_in, const int* in_sizes, int n_in,
                              void* d_out, int out_size, void* d_ws, size_t ws_size,
                              hipStream_t stream) {
    // setup_inputs order: t (int scalar), V, n, m, h, p  (each float32, B elems)
    const int*   t = (const int*)  d_in[0];
    const f32x4* V = (const f32x4*)d_in[1];
    const f32x4* n = (const f32x4*)d_in[2];
    const f32x4* m = (const f32x4*)d_in[3];
    const f32x4* h = (const f32x4*)d_in[4];
    const f32x4* p = (const f32x4*)d_in[5];

    int B   = in_sizes[1];     // 8388608, divisible by 8
    int nb4 = B / 4;
    int nb8 = nb4 / 2;

    // CURR_LEVEL / A_SOMA, A_SOMA = pi * (70e-4)^2
    float i_in = (float)(0.0005 / (3.141592653589793 * 70.0e-4 * 70.0e-4));

    int block = 256;
    int grid  = (nb8 + block - 1) / block;
    hh_kernel<<<grid, block, 0, stream>>>(t, V, n, m, h, p, (f32x4*)d_out, nb8, nb4, i_in);
}